// Round 3
// baseline (639.232 us; speedup 1.0000x reference)
//
#include <hip/hip_runtime.h>
#include <hip/hip_bf16.h>
#include <stdint.h>

#define BDIM 4
#define SDIM 1024
#define DDIM 1024
#define HDIM 16
#define DHDIM 64

typedef __bf16 bf16_t;
typedef __bf16 bf16x8 __attribute__((ext_vector_type(8)));
typedef __bf16 bf16x4 __attribute__((ext_vector_type(4)));
typedef float f32x4 __attribute__((ext_vector_type(4)));

typedef __attribute__((address_space(3))) uint32_t lds_u32;
typedef const __attribute__((address_space(1))) uint32_t glb_u32;

__device__ __forceinline__ void glds16(const void* g, void* l) {
    __builtin_amdgcn_global_load_lds((glb_u32*)g, (lds_u32*)l, 16, 0, 0);
}

// ---------------- conversions ----------------

__global__ __launch_bounds__(256) void convert_x_kernel(const float* __restrict__ X,
                                                        bf16_t* __restrict__ Xb, int n) {
    int i = (blockIdx.x * 256 + threadIdx.x) * 4;
    if (i >= n) return;
    float4 v = *(const float4*)(X + i);
    bf16x4 o;
    o[0] = (bf16_t)v.x; o[1] = (bf16_t)v.y; o[2] = (bf16_t)v.z; o[3] = (bf16_t)v.w;
    *(bf16x4*)(Xb + i) = o;
}

// W[k][n] fp32 -> Wt[n][k] bf16, for 4 weights (z selects)
__global__ __launch_bounds__(256) void transpose_w_kernel(const float* __restrict__ W0,
                                                          const float* __restrict__ W1,
                                                          const float* __restrict__ W2,
                                                          const float* __restrict__ W3,
                                                          bf16_t* __restrict__ Wt) {
    __shared__ float tile[32][33];
    int z = blockIdx.z;
    const float* W = (z == 0) ? W0 : (z == 1) ? W1 : (z == 2) ? W2 : W3;
    bf16_t* dst = Wt + (size_t)z * DDIM * DDIM;
    int bx = blockIdx.x * 32;  // n tile
    int by = blockIdx.y * 32;  // k tile
    int x = threadIdx.x & 31, y0 = threadIdx.x >> 5;
#pragma unroll
    for (int i = 0; i < 4; i++) {
        int y = y0 + i * 8;
        tile[y][x] = W[(size_t)(by + y) * DDIM + bx + x];
    }
    __syncthreads();
#pragma unroll
    for (int i = 0; i < 4; i++) {
        int y = y0 + i * 8;
        dst[(size_t)(bx + y) * DDIM + by + x] = (bf16_t)tile[x][y];
    }
}

// Detect mask element layout: uint8 bools -> bytes at i%4!=0 nonzero somewhere;
// int32 -> those bytes all 0. flag=1 means stride 1 (uint8), else stride 4.
__global__ __launch_bounds__(1024) void mask_flag_kernel(const unsigned char* __restrict__ mb,
                                                         int* __restrict__ flag) {
    __shared__ int any;
    if (threadIdx.x == 0) any = 0;
    __syncthreads();
    int loc = 0;
    for (int i = threadIdx.x; i < BDIM * SDIM; i += 1024)
        if ((i & 3) && mb[i]) loc = 1;
    if (loc) any = 1;
    __syncthreads();
    if (threadIdx.x == 0) *flag = any ? 1 : 0;
}

// ---------------- GEMM: C[m,n] = sum_k A[m,k] * Bt[n,k] (m97-style) ----------------
// MODE 0: write Q bf16 [B,H,S,DH] (scaled 0.125), K bf16 [B,H,S,DH], V TRANSPOSED
//         as Vt [B,H,DH,S]. N=3072.
// MODE 1: write fp32 C row-major [M,1024]
template <int MODE>
__global__ __launch_bounds__(256) void gemm_bt_kernel(const bf16_t* __restrict__ A,
                                                      const bf16_t* __restrict__ Bt,
                                                      bf16_t* __restrict__ Qo, bf16_t* __restrict__ Ko,
                                                      bf16_t* __restrict__ Vto, float* __restrict__ Co) {
    __shared__ bf16_t As[128 * 32];
    __shared__ bf16_t Bs[128 * 32];
    const int m0 = blockIdx.x * 128;
    const int n0 = blockIdx.y * 128;
    const int t = threadIdx.x;
    const int lane = t & 63, w = t >> 6;
    const int wm = w & 1, wn = w >> 1;
    const int low = lane & 15, quad = lane >> 4;
    f32x4 acc[4][4] = {};

    // global_load_lds: wave w stages rows [w*16, w*16+16); lds dest = base + lane*16B
    const int srow = w * 16 + (lane >> 2);
    const int koff = (lane & 3) * 8;
    const bf16_t* Ag = A + (size_t)(m0 + srow) * DDIM + koff;
    const bf16_t* Bg = Bt + (size_t)(n0 + srow) * DDIM + koff;
    bf16_t* AsW = As + w * 512;
    bf16_t* BsW = Bs + w * 512;

    for (int k0 = 0; k0 < DDIM; k0 += 32) {
        __syncthreads();
        glds16(Ag + k0, AsW);
        glds16(Ag + (size_t)64 * DDIM + k0, AsW + 64 * 32);
        glds16(Bg + k0, BsW);
        glds16(Bg + (size_t)64 * DDIM + k0, BsW + 64 * 32);
        __syncthreads();
        bf16x8 af[4], bv[4];
#pragma unroll
        for (int mt = 0; mt < 4; mt++)
            af[mt] = *(const bf16x8*)(As + (wm * 64 + mt * 16 + low) * 32 + quad * 8);
#pragma unroll
        for (int nt = 0; nt < 4; nt++)
            bv[nt] = *(const bf16x8*)(Bs + (wn * 64 + nt * 16 + low) * 32 + quad * 8);
#pragma unroll
        for (int mt = 0; mt < 4; mt++)
#pragma unroll
            for (int nt = 0; nt < 4; nt++)
                acc[mt][nt] = __builtin_amdgcn_mfma_f32_16x16x32_bf16(af[mt], bv[nt], acc[mt][nt], 0, 0, 0);
    }

#pragma unroll
    for (int mt = 0; mt < 4; mt++) {
#pragma unroll
        for (int nt = 0; nt < 4; nt++) {
#pragma unroll
            for (int r = 0; r < 4; r++) {
                int mrow = m0 + wm * 64 + mt * 16 + quad * 4 + r;
                int ncol = n0 + wn * 64 + nt * 16 + low;
                float vv = acc[mt][nt][r];
                if (MODE == 0) {
                    int which = ncol >> 10, nl = ncol & 1023;
                    int h = nl >> 6, dh = nl & 63;
                    int b = mrow >> 10, s = mrow & 1023;
                    if (which == 0)
                        Qo[((size_t)(b * HDIM + h) * SDIM + s) * DHDIM + dh] = (bf16_t)(vv * 0.125f);
                    else if (which == 1)
                        Ko[((size_t)(b * HDIM + h) * SDIM + s) * DHDIM + dh] = (bf16_t)vv;
                    else  // V transposed: Vt[b,h][dh][s]
                        Vto[((size_t)(b * HDIM + h) * DHDIM + dh) * SDIM + s] = (bf16_t)vv;
                } else {
                    Co[(size_t)mrow * DDIM + ncol] = vv;
                }
            }
        }
    }
}

// ---------------- fused attention, 16 heads per block ----------------
// grid: (S/16, B); block 512 = 8 waves; wave w handles heads {2w, 2w+1},
// q rows [q0, q0+16). Bias read directly from inter (coalesced, h innermost),
// staged per 64-key chunk into LDS as bf16 [h][k][q] with mask penalty folded.
__global__ __launch_bounds__(512) void attn_kernel(const bf16_t* __restrict__ Q,
                                                   const bf16_t* __restrict__ K,
                                                   const bf16_t* __restrict__ Vt,
                                                   const float* __restrict__ inter,
                                                   const unsigned char* __restrict__ maskb,
                                                   const int* __restrict__ flagp,
                                                   bf16_t* __restrict__ hid) {
    constexpr int KS = 20;            // k stride in bias tile (16 q + 4 pad), 40 B
    constexpr int HS = 64 * KS + 4;   // h stride = 1284 bf16 (2568 B, 8B-aligned)
    __shared__ bf16_t bias_l[16 * HS];   // ~41 KB
    __shared__ float pen_l[SDIM];        // 4 KB
    __shared__ bf16_t P[8][16 * 72];     // per-wave P tiles, 18 KB
    const int b = blockIdx.y;
    const int q0 = blockIdx.x * 16;
    const int t = threadIdx.x;
    const int w = t >> 6, lane = t & 63;
    const int low = lane & 15, quad = lane >> 4;
    const int h0 = w * 2;
    const int mstride = (*flagp) ? 1 : 4;

    // mask penalty for all 1024 keys
    for (int k = t; k < SDIM; k += 512)
        pen_l[k] = maskb[((size_t)b * SDIM + k) * mstride] ? 0.f : 1.0e9f;

    // Q fragments (A-operand), per wave-head
    bf16x8 qf[2][2];
#pragma unroll
    for (int hh = 0; hh < 2; hh++) {
        const bf16_t* Qb = Q + ((size_t)(b * HDIM + h0 + hh) * SDIM + q0) * DHDIM;
        qf[hh][0] = *(const bf16x8*)(Qb + low * DHDIM + quad * 8);
        qf[hh][1] = *(const bf16x8*)(Qb + low * DHDIM + 32 + quad * 8);
    }

    // bias staging assignment: thread covers q=t>>5, row floats [so + i*128]
    const int sq = t >> 5;
    const int so = (t & 31) * 4;
    const int hb = (t & 3) * 4;          // h base of each float4
    const int kb = (t & 31) >> 2;        // k_local base (+ 8*i)
    const float* srcQ = inter + ((size_t)(b * SDIM + q0 + sq) * SDIM) * HDIM + so;

    float4 regs[8];
#pragma unroll
    for (int i = 0; i < 8; i++) regs[i] = *(const float4*)(srcQ + i * 128);

    float mrow[2][4], lrow[2][4];
    f32x4 accO[2][4] = {};
#pragma unroll
    for (int hh = 0; hh < 2; hh++)
#pragma unroll
        for (int r = 0; r < 4; r++) { mrow[hh][r] = -3.0e38f; lrow[hh][r] = 0.f; }

    __syncthreads();  // pen_l ready

    for (int c = 0; c < SDIM / 64; c++) {
        // ---- write bias tile (chunk c) from regs into LDS ----
#pragma unroll
        for (int i = 0; i < 8; i++) {
            int kl = kb + i * 8;
            float p = pen_l[c * 64 + kl];
            float4 v = regs[i];
            bf16_t* d = bias_l + kl * KS + sq;
            d[(hb + 0) * HS] = (bf16_t)(v.x - p);
            d[(hb + 1) * HS] = (bf16_t)(v.y - p);
            d[(hb + 2) * HS] = (bf16_t)(v.z - p);
            d[(hb + 3) * HS] = (bf16_t)(v.w - p);
        }
        __syncthreads();  // bias tile visible
        // prefetch next chunk's bias while computing
        if (c + 1 < SDIM / 64) {
#pragma unroll
            for (int i = 0; i < 8; i++)
                regs[i] = *(const float4*)(srcQ + (c + 1) * 1024 + i * 128);
        }
        const int kbase = c * 64;
#pragma unroll
        for (int hh = 0; hh < 2; hh++) {
            const int h = h0 + hh;
            const bf16_t* Kb = K + (size_t)(b * HDIM + h) * SDIM * DHDIM;
            const bf16_t* VtB = Vt + (size_t)(b * HDIM + h) * DHDIM * SDIM;
            // S = Q K^T
            f32x4 sacc[4];
#pragma unroll
            for (int nt = 0; nt < 4; nt++) {
                const bf16_t* kp = Kb + (size_t)(kbase + nt * 16 + low) * DHDIM;
                bf16x8 kf0 = *(const bf16x8*)(kp + quad * 8);
                bf16x8 kf1 = *(const bf16x8*)(kp + 32 + quad * 8);
                f32x4 z = {};
                z = __builtin_amdgcn_mfma_f32_16x16x32_bf16(qf[hh][0], kf0, z, 0, 0, 0);
                z = __builtin_amdgcn_mfma_f32_16x16x32_bf16(qf[hh][1], kf1, z, 0, 0, 0);
                sacc[nt] = z;
            }
            // + bias (mask folded); C-layout: row q = quad*4+r, col k = nt*16+low
            float sv[4][4];
#pragma unroll
            for (int nt = 0; nt < 4; nt++) {
                bf16x4 bv = *(const bf16x4*)(bias_l + h * HS + (nt * 16 + low) * KS + quad * 4);
#pragma unroll
                for (int r = 0; r < 4; r++) sv[nt][r] = sacc[nt][r] + (float)bv[r];
            }
            // online softmax (rows within 16-lane low-group)
#pragma unroll
            for (int r = 0; r < 4; r++) {
                float vmx = fmaxf(fmaxf(sv[0][r], sv[1][r]), fmaxf(sv[2][r], sv[3][r]));
                vmx = fmaxf(vmx, __shfl_xor(vmx, 1));
                vmx = fmaxf(vmx, __shfl_xor(vmx, 2));
                vmx = fmaxf(vmx, __shfl_xor(vmx, 4));
                vmx = fmaxf(vmx, __shfl_xor(vmx, 8));
                float mn = fmaxf(mrow[hh][r], vmx);
                float alpha = __expf(mrow[hh][r] - mn);
                mrow[hh][r] = mn;
                lrow[hh][r] *= alpha;
#pragma unroll
                for (int nt = 0; nt < 4; nt++) accO[hh][nt][r] *= alpha;
                float rs = 0.f;
#pragma unroll
                for (int nt = 0; nt < 4; nt++) {
                    float p = __expf(sv[nt][r] - mn);
                    sv[nt][r] = p;
                    rs += p;
                }
                rs += __shfl_xor(rs, 1);
                rs += __shfl_xor(rs, 2);
                rs += __shfl_xor(rs, 4);
                rs += __shfl_xor(rs, 8);
                lrow[hh][r] += rs;
            }
            // P -> wave-private LDS (C-layout -> A-layout), no barrier needed
            bf16_t* Pw = &P[w][0];
#pragma unroll
            for (int nt = 0; nt < 4; nt++)
#pragma unroll
                for (int r = 0; r < 4; r++)
                    Pw[(quad * 4 + r) * 72 + nt * 16 + low] = (bf16_t)sv[nt][r];
            // O += P V   (V^T read as B-frag directly from global Vt)
#pragma unroll
            for (int step = 0; step < 2; step++) {
                bf16x8 pf = *(const bf16x8*)(Pw + low * 72 + step * 32 + quad * 8);
#pragma unroll
                for (int nt = 0; nt < 4; nt++) {
                    bf16x8 vf = *(const bf16x8*)(VtB + (size_t)(nt * 16 + low) * SDIM +
                                                 kbase + step * 32 + quad * 8);
                    accO[hh][nt] = __builtin_amdgcn_mfma_f32_16x16x32_bf16(pf, vf, accO[hh][nt], 0, 0, 0);
                }
            }
        }
        __syncthreads();  // all waves done with bias tile c
    }
    // epilogue: hidden[b, q, h*64+dh] bf16
#pragma unroll
    for (int hh = 0; hh < 2; hh++) {
#pragma unroll
        for (int r = 0; r < 4; r++) {
            float inv = 1.f / lrow[hh][r];
#pragma unroll
            for (int nt = 0; nt < 4; nt++) {
                hid[((size_t)b * SDIM + q0 + quad * 4 + r) * DDIM + (h0 + hh) * 64 + nt * 16 + low] =
                    (bf16_t)(accO[hh][nt][r] * inv);
            }
        }
    }
}

// ---------------- launcher ----------------

extern "C" void kernel_launch(void* const* d_in, const int* in_sizes, int n_in,
                              void* d_out, int out_size, void* d_ws, size_t ws_size,
                              hipStream_t stream) {
    const float* X = (const float*)d_in[0];
    const unsigned char* maskb = (const unsigned char*)d_in[1];
    const float* inter = (const float*)d_in[2];
    const float* WQ = (const float*)d_in[3];
    const float* WK = (const float*)d_in[4];
    const float* WV = (const float*)d_in[5];
    const float* WO = (const float*)d_in[6];
    float* out = (float*)d_out;

    char* ws = (char*)d_ws;
    const size_t MB = 1024 * 1024;
    bf16_t* Xb  = (bf16_t*)(ws + 0 * MB);
    bf16_t* Wt  = (bf16_t*)(ws + 8 * MB);    // [4][1024][1024] bf16 transposed
    bf16_t* Qm  = (bf16_t*)(ws + 16 * MB);   // [B,H,S,DH]
    bf16_t* Km  = (bf16_t*)(ws + 24 * MB);   // [B,H,S,DH]
    bf16_t* Vtm = (bf16_t*)(ws + 32 * MB);   // [B,H,DH,S]  (transposed V)
    bf16_t* hid = (bf16_t*)(ws + 40 * MB);   // [B,S,D] bf16
    int* flag   = (int*)(ws + 48 * MB);

    convert_x_kernel<<<BDIM * SDIM * DDIM / (256 * 4), 256, 0, stream>>>(X, Xb, BDIM * SDIM * DDIM);
    transpose_w_kernel<<<dim3(32, 32, 4), 256, 0, stream>>>(WQ, WK, WV, WO, Wt);
    mask_flag_kernel<<<1, 1024, 0, stream>>>(maskb, flag);
    // QKV projection: M=4096, N=3072 (Wt_Q|Wt_K|Wt_V contiguous)
    gemm_bt_kernel<0><<<dim3(32, 24), 256, 0, stream>>>(Xb, Wt, Qm, Km, Vtm, nullptr);
    // fused attention reading interaction bias directly
    attn_kernel<<<dim3(SDIM / 16, BDIM), 512, 0, stream>>>(Qm, Km, Vtm, inter, maskb, flag, hid);
    // output projection: M=4096, N=1024
    gemm_bt_kernel<1><<<dim3(32, 8), 256, 0, stream>>>(hid, Wt + (size_t)3 * DDIM * DDIM,
                                                       nullptr, nullptr, nullptr, out);
}

// Round 4
// 565.469 us; speedup vs baseline: 1.1304x; 1.1304x over previous
//
#include <hip/hip_runtime.h>
#include <hip/hip_bf16.h>
#include <stdint.h>

#define BDIM 4
#define SDIM 1024
#define DDIM 1024
#define HDIM 16
#define DHDIM 64

typedef __bf16 bf16_t;
typedef __bf16 bf16x8 __attribute__((ext_vector_type(8)));
typedef __bf16 bf16x4 __attribute__((ext_vector_type(4)));
typedef float f32x4 __attribute__((ext_vector_type(4)));

typedef __attribute__((address_space(3))) uint32_t lds_u32;
typedef const __attribute__((address_space(1))) uint32_t glb_u32;

__device__ __forceinline__ void glds16(const void* g, void* l) {
    __builtin_amdgcn_global_load_lds((glb_u32*)g, (lds_u32*)l, 16, 0, 0);
}

// ---------------- conversions ----------------

__global__ __launch_bounds__(256) void convert_x_kernel(const float* __restrict__ X,
                                                        bf16_t* __restrict__ Xb, int n) {
    int i = (blockIdx.x * 256 + threadIdx.x) * 4;
    if (i >= n) return;
    float4 v = *(const float4*)(X + i);
    bf16x4 o;
    o[0] = (bf16_t)v.x; o[1] = (bf16_t)v.y; o[2] = (bf16_t)v.z; o[3] = (bf16_t)v.w;
    *(bf16x4*)(Xb + i) = o;
}

// W[k][n] fp32 -> Wt[n][k] bf16, for 4 weights (z selects)
__global__ __launch_bounds__(256) void transpose_w_kernel(const float* __restrict__ W0,
                                                          const float* __restrict__ W1,
                                                          const float* __restrict__ W2,
                                                          const float* __restrict__ W3,
                                                          bf16_t* __restrict__ Wt) {
    __shared__ float tile[32][33];
    int z = blockIdx.z;
    const float* W = (z == 0) ? W0 : (z == 1) ? W1 : (z == 2) ? W2 : W3;
    bf16_t* dst = Wt + (size_t)z * DDIM * DDIM;
    int bx = blockIdx.x * 32;  // n tile
    int by = blockIdx.y * 32;  // k tile
    int x = threadIdx.x & 31, y0 = threadIdx.x >> 5;
#pragma unroll
    for (int i = 0; i < 4; i++) {
        int y = y0 + i * 8;
        tile[y][x] = W[(size_t)(by + y) * DDIM + bx + x];
    }
    __syncthreads();
#pragma unroll
    for (int i = 0; i < 4; i++) {
        int y = y0 + i * 8;
        dst[(size_t)(bx + y) * DDIM + by + x] = (bf16_t)tile[x][y];
    }
}

// Detect mask element layout: uint8 bools -> bytes at i%4!=0 nonzero somewhere;
// int32 -> those bytes all 0. flag=1 means stride 1 (uint8), else stride 4.
__global__ __launch_bounds__(1024) void mask_flag_kernel(const unsigned char* __restrict__ mb,
                                                         int* __restrict__ flag) {
    __shared__ int any;
    if (threadIdx.x == 0) any = 0;
    __syncthreads();
    int loc = 0;
    for (int i = threadIdx.x; i < BDIM * SDIM; i += 1024)
        if ((i & 3) && mb[i]) loc = 1;
    if (loc) any = 1;
    __syncthreads();
    if (threadIdx.x == 0) *flag = any ? 1 : 0;
}

// ---------------- GEMM: C[m,n] = sum_k A[m,k] * Bt[n,k] (m97-style) ----------------
// MODE 0: write Q bf16 [B,H,S,DH] (scaled 0.125), K bf16 [B,H,S,DH], V TRANSPOSED
//         as Vt [B,H,DH,S]. N=3072.
// MODE 1: write fp32 C row-major [M,1024]
template <int MODE>
__global__ __launch_bounds__(256) void gemm_bt_kernel(const bf16_t* __restrict__ A,
                                                      const bf16_t* __restrict__ Bt,
                                                      bf16_t* __restrict__ Qo, bf16_t* __restrict__ Ko,
                                                      bf16_t* __restrict__ Vto, float* __restrict__ Co) {
    __shared__ bf16_t As[128 * 32];
    __shared__ bf16_t Bs[128 * 32];
    const int m0 = blockIdx.x * 128;
    const int n0 = blockIdx.y * 128;
    const int t = threadIdx.x;
    const int lane = t & 63, w = t >> 6;
    const int wm = w & 1, wn = w >> 1;
    const int low = lane & 15, quad = lane >> 4;
    f32x4 acc[4][4] = {};

    // global_load_lds: wave w stages rows [w*16, w*16+16); lds dest = base + lane*16B
    const int srow = w * 16 + (lane >> 2);
    const int koff = (lane & 3) * 8;
    const bf16_t* Ag = A + (size_t)(m0 + srow) * DDIM + koff;
    const bf16_t* Bg = Bt + (size_t)(n0 + srow) * DDIM + koff;
    bf16_t* AsW = As + w * 512;
    bf16_t* BsW = Bs + w * 512;

    for (int k0 = 0; k0 < DDIM; k0 += 32) {
        __syncthreads();
        glds16(Ag + k0, AsW);
        glds16(Ag + (size_t)64 * DDIM + k0, AsW + 64 * 32);
        glds16(Bg + k0, BsW);
        glds16(Bg + (size_t)64 * DDIM + k0, BsW + 64 * 32);
        __syncthreads();
        bf16x8 af[4], bv[4];
#pragma unroll
        for (int mt = 0; mt < 4; mt++)
            af[mt] = *(const bf16x8*)(As + (wm * 64 + mt * 16 + low) * 32 + quad * 8);
#pragma unroll
        for (int nt = 0; nt < 4; nt++)
            bv[nt] = *(const bf16x8*)(Bs + (wn * 64 + nt * 16 + low) * 32 + quad * 8);
#pragma unroll
        for (int mt = 0; mt < 4; mt++)
#pragma unroll
            for (int nt = 0; nt < 4; nt++)
                acc[mt][nt] = __builtin_amdgcn_mfma_f32_16x16x32_bf16(af[mt], bv[nt], acc[mt][nt], 0, 0, 0);
    }

#pragma unroll
    for (int mt = 0; mt < 4; mt++) {
#pragma unroll
        for (int nt = 0; nt < 4; nt++) {
#pragma unroll
            for (int r = 0; r < 4; r++) {
                int mrow = m0 + wm * 64 + mt * 16 + quad * 4 + r;
                int ncol = n0 + wn * 64 + nt * 16 + low;
                float vv = acc[mt][nt][r];
                if (MODE == 0) {
                    int which = ncol >> 10, nl = ncol & 1023;
                    int h = nl >> 6, dh = nl & 63;
                    int b = mrow >> 10, s = mrow & 1023;
                    if (which == 0)
                        Qo[((size_t)(b * HDIM + h) * SDIM + s) * DHDIM + dh] = (bf16_t)(vv * 0.125f);
                    else if (which == 1)
                        Ko[((size_t)(b * HDIM + h) * SDIM + s) * DHDIM + dh] = (bf16_t)vv;
                    else  // V transposed: Vt[b,h][dh][s]
                        Vto[((size_t)(b * HDIM + h) * DHDIM + dh) * SDIM + s] = (bf16_t)vv;
                } else {
                    Co[(size_t)mrow * DDIM + ncol] = vv;
                }
            }
        }
    }
}

// ---------------- fused attention, 16 heads per block, 1 head per wave --------
// grid: (S/16, B); block 1024 = 16 waves; wave w = head w, q rows [q0, q0+16).
// 32-key chunks; bias tile double-buffered in LDS (bf16 [h][k][q], mask folded);
// ONE barrier per chunk: compute chunk c from buf[c&1], then stage chunk c+1
// into buf[(c+1)&1] from registers prefetched during compute.
__global__ __launch_bounds__(1024, 4) void attn_kernel(const bf16_t* __restrict__ Q,
                                                       const bf16_t* __restrict__ K,
                                                       const bf16_t* __restrict__ Vt,
                                                       const float* __restrict__ inter,
                                                       const unsigned char* __restrict__ maskb,
                                                       const int* __restrict__ flagp,
                                                       bf16_t* __restrict__ hid) {
    constexpr int KS = 20;            // k stride (16 q + 4 pad) in bf16
    constexpr int HS = 32 * KS + 4;   // h stride = 644 bf16
    __shared__ bf16_t bias_l[2][16 * HS];  // 2 x 20.6 KB
    __shared__ bf16_t P[16][16 * 40];      // per-wave P tiles (16q x 32k, pad 8), 20 KB
    const int b = blockIdx.y;
    const int q0 = blockIdx.x * 16;
    const int t = threadIdx.x;
    const int w = t >> 6, lane = t & 63;
    const int low = lane & 15, quad = lane >> 4;
    const int h = w;
    const int mstride = (*flagp) ? 1 : 4;

    // ---- per-thread bias staging coords: q row = w, 8 floats per chunk ----
    const int kl = lane >> 1;            // k_local (0..31)
    const int hb = (lane & 1) * 8;       // h base of the 8 floats
    const float* srcQ = inter + ((size_t)(b * SDIM + q0 + w) * SDIM) * HDIM + lane * 8;
    const unsigned char* mb = maskb + (size_t)b * SDIM * mstride;

    // Q fragments (A-operand) for head h
    const bf16_t* Qb = Q + ((size_t)(b * HDIM + h) * SDIM + q0) * DHDIM;
    bf16x8 qf0 = *(const bf16x8*)(Qb + low * DHDIM + quad * 8);
    bf16x8 qf1 = *(const bf16x8*)(Qb + low * DHDIM + 32 + quad * 8);

    const bf16_t* Kb = K + (size_t)(b * HDIM + h) * SDIM * DHDIM;
    const bf16_t* VtB = Vt + (size_t)(b * HDIM + h) * DHDIM * SDIM;
    bf16_t* Pw = &P[w][0];

    float mrow[4], lrow[4];
    f32x4 accO[4] = {};
#pragma unroll
    for (int r = 0; r < 4; r++) { mrow[r] = -3.0e38f; lrow[r] = 0.f; }

    // ---- prologue: load + stage chunk 0 into buf 0 ----
    float4 r0 = *(const float4*)(srcQ + 0);
    float4 r1 = *(const float4*)(srcQ + 4);
    float pcur = mb[kl * mstride] ? 0.f : 1.0e9f;
    {
        bf16_t* d = &bias_l[0][kl * KS + w];
        d[(hb + 0) * HS] = (bf16_t)(r0.x - pcur);
        d[(hb + 1) * HS] = (bf16_t)(r0.y - pcur);
        d[(hb + 2) * HS] = (bf16_t)(r0.z - pcur);
        d[(hb + 3) * HS] = (bf16_t)(r0.w - pcur);
        d[(hb + 4) * HS] = (bf16_t)(r1.x - pcur);
        d[(hb + 5) * HS] = (bf16_t)(r1.y - pcur);
        d[(hb + 6) * HS] = (bf16_t)(r1.z - pcur);
        d[(hb + 7) * HS] = (bf16_t)(r1.w - pcur);
    }

    for (int c = 0; c < SDIM / 32; c++) {
        __syncthreads();  // tile c visible; previous readers of buf[(c+1)&1] done
        const int kbase = c * 32;
        // prefetch chunk c+1 bias + mask (lands during compute below)
        float4 n0v, n1v; float pnext = 0.f;
        if (c + 1 < SDIM / 32) {
            n0v = *(const float4*)(srcQ + (c + 1) * 512 + 0);
            n1v = *(const float4*)(srcQ + (c + 1) * 512 + 4);
            pnext = mb[((c + 1) * 32 + kl) * mstride] ? 0.f : 1.0e9f;
        }
        // ---- S = Q K^T for 32 keys ----
        f32x4 sacc[2];
#pragma unroll
        for (int nt = 0; nt < 2; nt++) {
            const bf16_t* kp = Kb + (size_t)(kbase + nt * 16 + low) * DHDIM;
            bf16x8 kf0 = *(const bf16x8*)(kp + quad * 8);
            bf16x8 kf1 = *(const bf16x8*)(kp + 32 + quad * 8);
            f32x4 z = {};
            z = __builtin_amdgcn_mfma_f32_16x16x32_bf16(qf0, kf0, z, 0, 0, 0);
            z = __builtin_amdgcn_mfma_f32_16x16x32_bf16(qf1, kf1, z, 0, 0, 0);
            sacc[nt] = z;
        }
        // + bias (mask folded); C-layout row q = quad*4+r, col k = nt*16+low
        const bf16_t* bias_c = &bias_l[c & 1][h * HS];
        float sv[2][4];
#pragma unroll
        for (int nt = 0; nt < 2; nt++) {
            bf16x4 bv = *(const bf16x4*)(bias_c + (nt * 16 + low) * KS + quad * 4);
#pragma unroll
            for (int r = 0; r < 4; r++) sv[nt][r] = sacc[nt][r] + (float)bv[r];
        }
        // ---- online softmax (rows within 16-lane low group) ----
#pragma unroll
        for (int r = 0; r < 4; r++) {
            float vmx = fmaxf(sv[0][r], sv[1][r]);
            vmx = fmaxf(vmx, __shfl_xor(vmx, 1));
            vmx = fmaxf(vmx, __shfl_xor(vmx, 2));
            vmx = fmaxf(vmx, __shfl_xor(vmx, 4));
            vmx = fmaxf(vmx, __shfl_xor(vmx, 8));
            float mn = fmaxf(mrow[r], vmx);
            float alpha = __expf(mrow[r] - mn);
            mrow[r] = mn;
            lrow[r] *= alpha;
#pragma unroll
            for (int nt = 0; nt < 4; nt++) accO[nt][r] *= alpha;
            float p0 = __expf(sv[0][r] - mn);
            float p1 = __expf(sv[1][r] - mn);
            sv[0][r] = p0; sv[1][r] = p1;
            float rs = p0 + p1;
            rs += __shfl_xor(rs, 1);
            rs += __shfl_xor(rs, 2);
            rs += __shfl_xor(rs, 4);
            rs += __shfl_xor(rs, 8);
            lrow[r] += rs;
        }
        // ---- P (C-layout) -> wave-private LDS (A-layout), no barrier ----
#pragma unroll
        for (int nt = 0; nt < 2; nt++)
#pragma unroll
            for (int r = 0; r < 4; r++)
                Pw[(quad * 4 + r) * 40 + nt * 16 + low] = (bf16_t)sv[nt][r];
        // ---- O += P V (K=32 contraction; V^T B-frags direct from global) ----
        bf16x8 pf = *(const bf16x8*)(Pw + low * 40 + quad * 8);
#pragma unroll
        for (int nt = 0; nt < 4; nt++) {
            bf16x8 vf = *(const bf16x8*)(VtB + (size_t)(nt * 16 + low) * SDIM + kbase + quad * 8);
            accO[nt] = __builtin_amdgcn_mfma_f32_16x16x32_bf16(pf, vf, accO[nt], 0, 0, 0);
        }
        // ---- stage chunk c+1 into the other buffer ----
        if (c + 1 < SDIM / 32) {
            bf16_t* d = &bias_l[(c + 1) & 1][kl * KS + w];
            d[(hb + 0) * HS] = (bf16_t)(n0v.x - pnext);
            d[(hb + 1) * HS] = (bf16_t)(n0v.y - pnext);
            d[(hb + 2) * HS] = (bf16_t)(n0v.z - pnext);
            d[(hb + 3) * HS] = (bf16_t)(n0v.w - pnext);
            d[(hb + 4) * HS] = (bf16_t)(n1v.x - pnext);
            d[(hb + 5) * HS] = (bf16_t)(n1v.y - pnext);
            d[(hb + 6) * HS] = (bf16_t)(n1v.z - pnext);
            d[(hb + 7) * HS] = (bf16_t)(n1v.w - pnext);
        }
    }
    // epilogue: hidden[b, q, h*64+dh] bf16
#pragma unroll
    for (int r = 0; r < 4; r++) {
        float inv = 1.f / lrow[r];
#pragma unroll
        for (int nt = 0; nt < 4; nt++) {
            hid[((size_t)b * SDIM + q0 + quad * 4 + r) * DDIM + h * 64 + nt * 16 + low] =
                (bf16_t)(accO[nt][r] * inv);
        }
    }
}

// ---------------- launcher ----------------

extern "C" void kernel_launch(void* const* d_in, const int* in_sizes, int n_in,
                              void* d_out, int out_size, void* d_ws, size_t ws_size,
                              hipStream_t stream) {
    const float* X = (const float*)d_in[0];
    const unsigned char* maskb = (const unsigned char*)d_in[1];
    const float* inter = (const float*)d_in[2];
    const float* WQ = (const float*)d_in[3];
    const float* WK = (const float*)d_in[4];
    const float* WV = (const float*)d_in[5];
    const float* WO = (const float*)d_in[6];
    float* out = (float*)d_out;

    char* ws = (char*)d_ws;
    const size_t MB = 1024 * 1024;
    bf16_t* Xb  = (bf16_t*)(ws + 0 * MB);
    bf16_t* Wt  = (bf16_t*)(ws + 8 * MB);    // [4][1024][1024] bf16 transposed
    bf16_t* Qm  = (bf16_t*)(ws + 16 * MB);   // [B,H,S,DH]
    bf16_t* Km  = (bf16_t*)(ws + 24 * MB);   // [B,H,S,DH]
    bf16_t* Vtm = (bf16_t*)(ws + 32 * MB);   // [B,H,DH,S]  (transposed V)
    bf16_t* hid = (bf16_t*)(ws + 40 * MB);   // [B,S,D] bf16
    int* flag   = (int*)(ws + 48 * MB);

    convert_x_kernel<<<BDIM * SDIM * DDIM / (256 * 4), 256, 0, stream>>>(X, Xb, BDIM * SDIM * DDIM);
    transpose_w_kernel<<<dim3(32, 32, 4), 256, 0, stream>>>(WQ, WK, WV, WO, Wt);
    mask_flag_kernel<<<1, 1024, 0, stream>>>(maskb, flag);
    // QKV projection: M=4096, N=3072 (Wt_Q|Wt_K|Wt_V contiguous)
    gemm_bt_kernel<0><<<dim3(32, 24), 256, 0, stream>>>(Xb, Wt, Qm, Km, Vtm, nullptr);
    // fused attention reading interaction bias directly
    attn_kernel<<<dim3(SDIM / 16, BDIM), 1024, 0, stream>>>(Qm, Km, Vtm, inter, maskb, flag, hid);
    // output projection: M=4096, N=1024
    gemm_bt_kernel<1><<<dim3(32, 8), 256, 0, stream>>>(hid, Wt + (size_t)3 * DDIM * DDIM,
                                                       nullptr, nullptr, nullptr, out);
}